// Round 3
// baseline (239.732 us; speedup 1.0000x reference)
//
#include <hip/hip_runtime.h>

#define T_LEN 200
#define F_IN  32
#define CH    10                  // 200 = 20 chunks of 10
#define NCH   (T_LEN / CH)
#define GSTRIDE (CH * F_IN + 4)   // 324 floats; pad staggers group bank offsets
#define BUFSZ   (16 * GSTRIDE)    // floats per LDS buffer (20736 B)

#define QP(a,b,c,d) ((a)|((b)<<2)|((c)<<4)|((d)<<6))
#define DPP_RM 0x140  // row_mirror: src lane = 15 - lane (within row of 16)
#define DPP_HM 0x141  // row_half_mirror: src lane = lane ^ 7 (within 8)

template <int CTRL>
__device__ __forceinline__ float dppf(float v) {
    return __int_as_float(__builtin_amdgcn_update_dpp(
        0, __float_as_int(v), CTRL, 0xF, 0xF, true));
}
// value from lane^8 (stays inside a row of 16): RM then HM => src = lane^15^7 = lane^8
__device__ __forceinline__ float xor8f(float v) {
    return dppf<DPP_HM>(dppf<DPP_RM>(v));
}

__launch_bounds__(256, 1)
__global__ void mono_lstm_kernel(const float* __restrict__ x,
                                 const float* __restrict__ z0,
                                 const float* __restrict__ W_ih,
                                 const float* __restrict__ W_hh,
                                 const float* __restrict__ b_ih,
                                 const float* __restrict__ b_hh,
                                 const float* __restrict__ W1,
                                 const float* __restrict__ b1,
                                 const float* __restrict__ W2,
                                 const float* __restrict__ b2,
                                 float* __restrict__ out) {
    __shared__ float xs[2 * BUFSZ];

    const int tid = threadIdx.x;
    const int l16 = tid & 15;   // lane within 16-lane group (1 batch elem)
    const int j   = l16 & 7;    // hidden unit
    const int p   = l16 >> 3;   // 0: rows (i_j, g_j)   1: rows (f_j, o_j)
    const int grp = tid >> 4;   // 16 batch elems per block
    const int b   = blockIdx.x * 16 + grp;

    const float LOG2E = 1.4426950408889634f;
    const float scA = LOG2E;                       // i,f rows: sigmoid
    const float scB = p ? LOG2E : 2.0f * LOG2E;    // o: sigmoid; g: tanh = 2*sig(2x)-1
    const int rowA = 8 * p + j;        // i (p=0) / f (p=1)
    const int rowB = 8 * (p + 2) + j;  // g (p=0) / o (p=1)

    // prescaled weights: activation becomes exp2 -> add -> rcp (-> fma for g)
    float wia[32], wib[32];
#pragma unroll
    for (int k = 0; k < 32; ++k) {
        wia[k] = W_ih[rowA * 33 + k] * scA;
        wib[k] = W_ih[rowB * 33 + k] * scB;
    }
    const float wza = W_ih[rowA * 33 + 32] * scA;
    const float wzb = W_ih[rowB * 33 + 32] * scB;
    const float bba = (b_ih[rowA] + b_hh[rowA]) * scA;
    const float bbb = (b_ih[rowB] + b_hh[rowB]) * scB;

    float wha[8], whb[8];   // xor-ordered: pairs with ha[k] = h_{j^k}
#pragma unroll
    for (int k = 0; k < 8; ++k) {
        wha[k] = W_hh[rowA * 8 + (j ^ k)] * scA;
        whb[k] = W_hh[rowB * 8 + (j ^ k)] * scB;
    }

    // head: lane computes d_m for m = j (inactive if m >= 5)
    float w1r[8];
    float b1r = 0.0f, w2r = 0.0f;
#pragma unroll
    for (int k = 0; k < 8; ++k) w1r[k] = 0.0f;
    if (j < 5) {
#pragma unroll
        for (int k = 0; k < 8; ++k) w1r[k] = W1[j * 8 + (j ^ k)];
        b1r = b1[j];
        w2r = W2[j];
    }
    const float b2v = b2[0];
    const float kb2 = p ? 1.0f : 2.0f;   // post-activation map for slot B
    const float kb1 = p ? 0.0f : -1.0f;

    float ha0 = 0.f, ha1 = 0.f, ha2 = 0.f, ha3 = 0.f,
          ha4 = 0.f, ha5 = 0.f, ha6 = 0.f, ha7 = 0.f;  // h_{j^k}
    float c = 0.0f;
    float z = z0[b];
    float zA = 0.0f;

    const float* xg   = x + (size_t)blockIdx.x * 16 * T_LEN * F_IN;
    float*       outg = out + (size_t)b * T_LEN;

    // ---- prologue: stage chunk 0 (exactly 5 float4 per thread) ----
#pragma unroll
    for (int it = 0; it < 5; ++it) {
        const int e4  = tid + it * 256;       // [0, 1280)
        const int g   = e4 / 80;              // 80 float4 per group per chunk
        const int rem = e4 - g * 80;
        const float4 v = *(const float4*)&xg[(size_t)g * T_LEN * F_IN + rem * 4];
        *(float4*)&xs[g * GSTRIDE + rem * 4] = v;
    }
    __syncthreads();

    for (int ch = 0; ch < NCH; ++ch) {
        // issue next chunk's global loads immediately (latency hidden by compute)
        float4 rg[5];
        if (ch + 1 < NCH) {
#pragma unroll
            for (int it = 0; it < 5; ++it) {
                const int e4  = tid + it * 256;
                const int g   = e4 / 80;
                const int rem = e4 - g * 80;
                rg[it] = *(const float4*)&xg[(size_t)g * T_LEN * F_IN +
                                             (ch + 1) * CH * F_IN + rem * 4];
            }
        }

        const float* xb = &xs[(ch & 1) * BUFSZ + grp * GSTRIDE];
#pragma unroll
        for (int tt = 0; tt < CH; ++tt) {
            // ---- off-chain: x-dot for both rows (broadcast LDS reads) ----
            float pa = bba, pb = bbb;
#pragma unroll
            for (int q = 0; q < 8; ++q) {
                const float4 xv = *(const float4*)&xb[tt * F_IN + 4 * q];
                pa = fmaf(wia[4 * q + 0], xv.x, pa);
                pa = fmaf(wia[4 * q + 1], xv.y, pa);
                pa = fmaf(wia[4 * q + 2], xv.z, pa);
                pa = fmaf(wia[4 * q + 3], xv.w, pa);
                pb = fmaf(wib[4 * q + 0], xv.x, pb);
                pb = fmaf(wib[4 * q + 1], xv.y, pb);
                pb = fmaf(wib[4 * q + 2], xv.z, pb);
                pb = fmaf(wib[4 * q + 3], xv.w, pb);
            }

            // ---- chain: recurrent matvec (two 2-deep sub-chains per row) ----
            float a0 = fmaf(wha[0], ha0, pa);
            float a1 = fmaf(wha[1], ha1, wha[2] * ha2);
            a0 = fmaf(wha[3], ha3, a0);
            a1 = fmaf(wha[4], ha4, a1);
            a0 = fmaf(wha[5], ha5, a0);
            a1 = fmaf(wha[6], ha6, a1);
            a0 = fmaf(wha[7], ha7, a0);
            const float accA = fmaf(wza, z, a0 + a1);

            float c0 = fmaf(whb[0], ha0, pb);
            float c1 = fmaf(whb[1], ha1, whb[2] * ha2);
            c0 = fmaf(whb[3], ha3, c0);
            c1 = fmaf(whb[4], ha4, c1);
            c0 = fmaf(whb[5], ha5, c0);
            c1 = fmaf(whb[6], ha6, c1);
            c0 = fmaf(whb[7], ha7, c0);
            const float accB = fmaf(wzb, z, c0 + c1);

            // activations (weights prescaled by log2e / 2log2e)
            const float sA = __builtin_amdgcn_rcpf(1.0f + __builtin_amdgcn_exp2f(-accA));
            const float sB = __builtin_amdgcn_rcpf(1.0f + __builtin_amdgcn_exp2f(-accB));
            const float aA = sA;                      // sigmoid(i) or sigmoid(f)
            const float aB = fmaf(kb2, sB, kb1);      // tanh(g) or sigmoid(o)

            // pair exchange across lane^8 (DPP only)
            const float oA = xor8f(aA);
            const float oB = xor8f(aB);
            const float iv = p ? oA : aA;
            const float fv = p ? aA : oA;
            const float gv = p ? oB : aB;
            const float ov = p ? aB : oB;

            c = fmaf(fv, c, iv * gv);
            const float et = __builtin_amdgcn_exp2f(c * (-2.0f * LOG2E));
            const float tc = fmaf(2.0f, __builtin_amdgcn_rcpf(1.0f + et), -1.0f);
            const float hn = ov * tc;   // h_j (replicated on both p-halves)

            // gather h_{j^k}, all within rows of 8 => pure DPP
            ha0 = hn;
            ha1 = dppf<QP(1, 0, 3, 2)>(hn);
            ha2 = dppf<QP(2, 3, 0, 1)>(hn);
            ha3 = dppf<QP(3, 2, 1, 0)>(hn);
            const float t7 = dppf<DPP_HM>(hn);   // h_{j^7}
            ha7 = t7;
            ha4 = dppf<QP(3, 2, 1, 0)>(t7);      // h_{j^4}
            ha5 = dppf<QP(2, 3, 0, 1)>(t7);      // h_{j^5}
            ha6 = dppf<QP(1, 0, 3, 2)>(t7);      // h_{j^6}

            // head: d_j on lane j; reduce w2*d over the 8-lane row
            float dA = fmaf(w1r[0], ha0, fmaf(w1r[1], ha1, fmaf(w1r[2], ha2, b1r)));
            float dB = fmaf(w1r[4], ha4, fmaf(w1r[5], ha5,
                       fmaf(w1r[6], ha6, w1r[7] * ha7)));
            const float d  = fmaxf(fmaf(w1r[3], ha3, dA + dB), 0.0f);
            float r = w2r * d;
            r += dppf<QP(1, 0, 3, 2)>(r);
            r += dppf<QP(2, 3, 0, 1)>(r);
            r += dppf<DPP_HM>(r);
            const float delta = fmaxf(r + b2v, 0.0f);
            z += delta;

            zA = (l16 == tt) ? z : zA;
        }

        if (l16 < CH) outg[ch * CH + l16] = zA;

        if (ch + 1 < NCH) {
            // write next chunk into the other buffer; safe: its previous readers
            // (chunk ch-1) finished before the sync that started this iteration
#pragma unroll
            for (int it = 0; it < 5; ++it) {
                const int e4  = tid + it * 256;
                const int g   = e4 / 80;
                const int rem = e4 - g * 80;
                *(float4*)&xs[((ch + 1) & 1) * BUFSZ + g * GSTRIDE + rem * 4] = rg[it];
            }
            __syncthreads();
        }
    }
}

extern "C" void kernel_launch(void* const* d_in, const int* in_sizes, int n_in,
                              void* d_out, int out_size, void* d_ws, size_t ws_size,
                              hipStream_t stream) {
    const float* x    = (const float*)d_in[0];
    const float* z0   = (const float*)d_in[1];
    const float* W_ih = (const float*)d_in[2];
    const float* W_hh = (const float*)d_in[3];
    const float* b_ih = (const float*)d_in[4];
    const float* b_hh = (const float*)d_in[5];
    const float* W1   = (const float*)d_in[6];
    const float* b1   = (const float*)d_in[7];
    const float* W2   = (const float*)d_in[8];
    const float* b2   = (const float*)d_in[9];
    float* out = (float*)d_out;

    const int B = in_sizes[1];
    dim3 grid(B / 16), block(256);
    hipLaunchKernelGGL(mono_lstm_kernel, grid, block, 0, stream,
                       x, z0, W_ih, W_hh, b_ih, b_hh, W1, b1, W2, b2, out);
}

// Round 4
// 230.128 us; speedup vs baseline: 1.0417x; 1.0417x over previous
//
#include <hip/hip_runtime.h>

#define T_LEN 200
#define F_IN  32
#define TC    8                 // timesteps per chunk; 200 = 25 * 8
#define NCH   (T_LEN / TC)
#define BPB   16                // batches per 512-thread block
#define XSTR  260               // x LDS stride per batch (floats); %32=4 breaks conflicts
#define PSTR  260
#define ZSTR  204

#define QP(a,b,c,d) ((a)|((b)<<2)|((c)<<4)|((d)<<6))
#define DPP_RM 0x140            // row_mirror: lane^15 within row16
#define DPP_HM 0x141            // row_half_mirror: lane^7 within row16

typedef short  bf16x8  __attribute__((ext_vector_type(8)));
typedef float  floatx4 __attribute__((ext_vector_type(4)));

template <int CTRL>
__device__ __forceinline__ float dppf(float v) {
    return __int_as_float(__builtin_amdgcn_update_dpp(
        0, __float_as_int(v), CTRL, 0xF, 0xF, true));
}
__device__ __forceinline__ float xor8f(float v) {   // value from lane^8 (in row16)
    return dppf<DPP_HM>(dppf<DPP_RM>(v));
}
__device__ __forceinline__ float swz16(float v) {   // value from lane^16 (in 32-half)
    return __int_as_float(__builtin_amdgcn_ds_swizzle(__float_as_int(v), 0x401F));
}
__device__ __forceinline__ unsigned short f2bf(float f) {  // fp32 -> bf16 RNE
    unsigned u = __float_as_uint(f);
    return (unsigned short)((u + 0x7FFFu + ((u >> 16) & 1u)) >> 16);
}
__device__ __forceinline__ float bf2f(unsigned short h) {
    return __uint_as_float(((unsigned)h) << 16);
}

__launch_bounds__(512, 2)
__global__ void mono_lstm_kernel(const float* __restrict__ x,
                                 const float* __restrict__ z0,
                                 const float* __restrict__ W_ih,
                                 const float* __restrict__ W_hh,
                                 const float* __restrict__ b_ih,
                                 const float* __restrict__ b_hh,
                                 const float* __restrict__ W1,
                                 const float* __restrict__ b1,
                                 const float* __restrict__ W2,
                                 const float* __restrict__ b2,
                                 float* __restrict__ out) {
    __shared__ float xls[BPB * XSTR];   // staged x chunk
    __shared__ float pls[BPB * PSTR];   // P = scaled(W_ih[:, :32] . x_t + bias)
    __shared__ float zls[BPB * ZSTR];   // z output buffer

    const int tid  = threadIdx.x;
    const int lane = tid & 31;
    const int grp  = tid >> 5;          // batch within block (0..15)
    const int j    = lane & 7;          // hidden unit
    const int q    = lane >> 3;         // 0=i 1=g 2=f 3=o  (permuted gate order!)
    const int wid  = tid >> 6;          // wave id (0..7) == its MFMA timestep
    const int l64  = tid & 63;
    const int bg   = blockIdx.x * BPB;

    const float L2E = 1.4426950408889634f;
    const float sc  = (q == 1) ? 2.0f * L2E : L2E;   // fold sigmoid/tanh arg scaling
    const int   r   = (q == 0 ? 0 : q == 1 ? 16 : q == 2 ? 8 : 24) + j;  // torch row

    float whh[8];
#pragma unroll
    for (int k = 0; k < 8; ++k) whh[k] = W_hh[r * 8 + (j ^ k)] * sc;
    const float wihz = W_ih[r * 33 + 32] * sc;

    float w1r[8]; float b1r = 0.f, w2r = 0.f;
#pragma unroll
    for (int k = 0; k < 8; ++k) w1r[k] = 0.f;
    if (j < 5) {
#pragma unroll
        for (int k = 0; k < 8; ++k) w1r[k] = W1[j * 8 + (j ^ k)];
        b1r = b1[j]; w2r = W2[j];
    }
    const float b2v = b2[0];
    const float kA = (q == 1) ? 2.0f : 1.0f;
    const float kB = (q == 1) ? -1.0f : 0.0f;
    const bool qi = (q == 0), qf = (q == 2), row0 = (q < 2);

    // ---- MFMA B fragments: W_ih cols 0..31, prescaled, hi/lo bf16 split ----
    // N-tile0 covers lane-order rows 0..15 (i0-7, g0-7); tile1: 16..31 (f, o).
    const int ln = l64 & 15;            // n within tile
    const int kq = l64 >> 4;            // K-quad
    const int rt0 = (ln < 8 ? 0 : 16) + (ln & 7);
    const int rt1 = (ln < 8 ? 8 : 24) + (ln & 7);
    const float sc0 = (ln < 8) ? L2E : 2.0f * L2E;
    const float sc1 = L2E;
    bf16x8 Bh0, Bl0, Bh1, Bl1;
#pragma unroll
    for (int i = 0; i < 8; ++i) {
        const int k = kq * 8 + i;
        const float w0 = W_ih[rt0 * 33 + k] * sc0;
        const unsigned short h0 = f2bf(w0);
        Bh0[i] = (short)h0; Bl0[i] = (short)f2bf(w0 - bf2f(h0));
        const float w1v = W_ih[rt1 * 33 + k] * sc1;
        const unsigned short h1 = f2bf(w1v);
        Bh1[i] = (short)h1; Bl1[i] = (short)f2bf(w1v - bf2f(h1));
    }
    const float bias0 = (b_ih[rt0] + b_hh[rt0]) * sc0;
    const float bias1 = (b_ih[rt1] + b_hh[rt1]) * sc1;

    float4 rg[2];
    auto load_x = [&](int c) {
#pragma unroll
        for (int it = 0; it < 2; ++it) {
            const int e4 = tid + it * 512;
            const int bl = e4 >> 6, rem = e4 & 63;
            rg[it] = *(const float4*)&x[(size_t)(bg + bl) * T_LEN * F_IN +
                                        c * TC * F_IN + rem * 4];
        }
    };
    auto store_x = [&]() {
#pragma unroll
        for (int it = 0; it < 2; ++it) {
            const int e4 = tid + it * 512;
            const int bl = e4 >> 6, rem = e4 & 63;
            *(float4*)&xls[bl * XSTR + rem * 4] = rg[it];
        }
    };
    auto mfma_phase = [&]() {
        // wave `wid` computes P for timestep t=wid of the chunk.
        const int m = l64 & 15;         // batch
        const float4 v0 = *(const float4*)&xls[m * XSTR + wid * 32 + kq * 8];
        const float4 v1 = *(const float4*)&xls[m * XSTR + wid * 32 + kq * 8 + 4];
        const float xv[8] = {v0.x, v0.y, v0.z, v0.w, v1.x, v1.y, v1.z, v1.w};
        bf16x8 Ah, Al;
#pragma unroll
        for (int i = 0; i < 8; ++i) {
            const unsigned short h = f2bf(xv[i]);
            Ah[i] = (short)h; Al[i] = (short)f2bf(xv[i] - bf2f(h));
        }
        floatx4 acc0 = {bias0, bias0, bias0, bias0};
        floatx4 acc1 = {bias1, bias1, bias1, bias1};
        acc0 = __builtin_amdgcn_mfma_f32_16x16x32_bf16(Ah, Bh0, acc0, 0, 0, 0);
        acc0 = __builtin_amdgcn_mfma_f32_16x16x32_bf16(Al, Bh0, acc0, 0, 0, 0);
        acc0 = __builtin_amdgcn_mfma_f32_16x16x32_bf16(Ah, Bl0, acc0, 0, 0, 0);
        acc1 = __builtin_amdgcn_mfma_f32_16x16x32_bf16(Ah, Bh1, acc1, 0, 0, 0);
        acc1 = __builtin_amdgcn_mfma_f32_16x16x32_bf16(Al, Bh1, acc1, 0, 0, 0);
        acc1 = __builtin_amdgcn_mfma_f32_16x16x32_bf16(Ah, Bl1, acc1, 0, 0, 0);
#pragma unroll
        for (int reg = 0; reg < 4; ++reg) {
            const int mb = (l64 >> 4) * 4 + reg;   // batch (C/D layout)
            pls[mb * PSTR + wid * 32 + ln]      = acc0[reg];
            pls[mb * PSTR + wid * 32 + 16 + ln] = acc1[reg];
        }
    };

    // ---- prologue ----
    load_x(0);
    store_x();
    __syncthreads();
    mfma_phase();                 // P(chunk 0)
    load_x(1);
    __syncthreads();

    float ha0 = 0.f, ha1 = 0.f, ha2 = 0.f, ha3 = 0.f,
          ha4 = 0.f, ha5 = 0.f, ha6 = 0.f, ha7 = 0.f;  // h_{j^k}
    float c = 0.0f;
    float z = z0[bg + grp];

    for (int ch = 0; ch < NCH; ++ch) {
        float pv[TC];
#pragma unroll
        for (int t = 0; t < TC; ++t) pv[t] = pls[grp * PSTR + t * 32 + lane];

#pragma unroll
        for (int t = 0; t < TC; ++t) {
            // recurrent matvec (pre-activation already scaled by L2E / 2L2E)
            float a0 = fmaf(whh[0], ha0, pv[t]);
            float a1 = fmaf(whh[1], ha1, whh[2] * ha2);
            a0 = fmaf(whh[3], ha3, a0);
            a1 = fmaf(whh[4], ha4, a1);
            a0 = fmaf(whh[5], ha5, a0);
            a1 = fmaf(whh[6], ha6, a1);
            a0 = fmaf(whh[7], ha7, a0);
            const float acc = fmaf(wihz, z, a0 + a1);

            const float sg = __builtin_amdgcn_rcpf(1.0f + __builtin_amdgcn_exp2f(-acc));
            const float a  = fmaf(kA, sg, kB);   // sigmoid, or tanh on g-lanes

            // i<->g and f<->o exchange (lane^8, DPP); then one lane^16 swizzle
            const float px    = xor8f(a);
            const float sendv = row0 ? a * px : a;   // row0 sends A=sig(i)*tanh(g)
            const float recv  = swz16(sendv);
            const float rx    = xor8f(recv);

            const float Aall = row0 ? a * px : recv;
            const float sf   = row0 ? (qi ? recv : rx) : (qf ? a : px);
            const float so   = row0 ? (qi ? rx : recv) : (qf ? px : a);

            c = fmaf(sf, c, Aall);
            const float e  = __builtin_amdgcn_exp2f(c * (-2.0f * L2E));
            const float tc = fmaf(2.0f, __builtin_amdgcn_rcpf(1.0f + e), -1.0f);
            const float hn = so * tc;            // h_j on every lane

            ha0 = hn;
            ha1 = dppf<QP(1, 0, 3, 2)>(hn);
            ha2 = dppf<QP(2, 3, 0, 1)>(hn);
            ha3 = dppf<QP(3, 2, 1, 0)>(hn);
            const float t7 = dppf<DPP_HM>(hn);
            ha7 = t7;
            ha4 = dppf<QP(3, 2, 1, 0)>(t7);
            ha5 = dppf<QP(2, 3, 0, 1)>(t7);
            ha6 = dppf<QP(1, 0, 3, 2)>(t7);

            // head: d_{m=j} on every lane; sum w2*d over the 8-lane group
            float d0 = fmaf(w1r[0], ha0, fmaf(w1r[1], ha1, fmaf(w1r[2], ha2, b1r)));
            float d1 = fmaf(w1r[4], ha4, fmaf(w1r[5], ha5,
                       fmaf(w1r[6], ha6, w1r[7] * ha7)));
            const float d = fmaxf(fmaf(w1r[3], ha3, d0 + d1), 0.0f);
            float rr = w2r * d;
            rr += dppf<QP(1, 0, 3, 2)>(rr);
            rr += dppf<QP(2, 3, 0, 1)>(rr);
            rr += dppf<DPP_HM>(rr);
            z += fmaxf(rr + b2v, 0.0f);

            if (lane == t) zls[grp * ZSTR + ch * TC + t] = z;
        }

        if (ch + 1 < NCH) {
            __syncthreads();                 // pv reads done -> pls/xls reusable
            store_x();                       // x(ch+1)
            if (ch + 2 < NCH) load_x(ch + 2);
            __syncthreads();                 // xls visible
            mfma_phase();                    // P(ch+1)
            __syncthreads();                 // pls visible for next iteration
        }
    }

    __syncthreads();
#pragma unroll
    for (int it = 0; it < 2; ++it) {
        const int e4 = tid + it * 512;
        if (e4 < BPB * (T_LEN / 4)) {        // 800 float4
            const int bl = e4 / 50, rem = e4 - bl * 50;
            *(float4*)&out[(size_t)(bg + bl) * T_LEN + rem * 4] =
                *(const float4*)&zls[bl * ZSTR + rem * 4];
        }
    }
}

extern "C" void kernel_launch(void* const* d_in, const int* in_sizes, int n_in,
                              void* d_out, int out_size, void* d_ws, size_t ws_size,
                              hipStream_t stream) {
    const float* x    = (const float*)d_in[0];
    const float* z0   = (const float*)d_in[1];
    const float* W_ih = (const float*)d_in[2];
    const float* W_hh = (const float*)d_in[3];
    const float* b_ih = (const float*)d_in[4];
    const float* b_hh = (const float*)d_in[5];
    const float* W1   = (const float*)d_in[6];
    const float* b1   = (const float*)d_in[7];
    const float* W2   = (const float*)d_in[8];
    const float* b2   = (const float*)d_in[9];
    float* out = (float*)d_out;

    const int B = in_sizes[1];
    dim3 grid(B / BPB), block(512);
    hipLaunchKernelGGL(mono_lstm_kernel, grid, block, 0, stream,
                       x, z0, W_ih, W_hh, b_ih, b_hh, W1, b1, W2, b2, out);
}

// Round 5
// 218.583 us; speedup vs baseline: 1.0968x; 1.0528x over previous
//
#include <hip/hip_runtime.h>

#define T_LEN 200
#define F_IN  32
#define TC    8                 // timesteps per chunk; 200 = 25 * 8
#define NCH   (T_LEN / TC)
#define PSTR  260               // P stride per batch (dwords): 8t*32 + pad
#define ZSTR  204               // z stride per batch (dwords), 16B-aligned rows

#define QP(a,b,c,d) ((a)|((b)<<2)|((c)<<4)|((d)<<6))
#define DPP_HM 0x141            // row_half_mirror: lane^7 within each 8-group

typedef short  bf16x8  __attribute__((ext_vector_type(8)));
typedef float  floatx4 __attribute__((ext_vector_type(4)));

template <int CTRL>
__device__ __forceinline__ float dppf(float v) {
    return __int_as_float(__builtin_amdgcn_update_dpp(
        0, __float_as_int(v), CTRL, 0xF, 0xF, true));
}
// truncation bf16 split: x ~= hi + lo, |err| ~ 2^-16 rel
__device__ __forceinline__ void bfsplit(float x, short& hi, short& lo) {
    unsigned u = __float_as_uint(x);
    unsigned short h = (unsigned short)(u >> 16);
    float fh = __uint_as_float(((unsigned)h) << 16);
    float r  = x - fh;
    hi = (short)h;
    lo = (short)(__float_as_uint(r) >> 16);
}

__launch_bounds__(64, 1)
__global__ void mono_lstm_kernel(const float* __restrict__ x,
                                 const float* __restrict__ z0,
                                 const float* __restrict__ W_ih,
                                 const float* __restrict__ W_hh,
                                 const float* __restrict__ b_ih,
                                 const float* __restrict__ b_hh,
                                 const float* __restrict__ W1,
                                 const float* __restrict__ b1,
                                 const float* __restrict__ W2,
                                 const float* __restrict__ b2,
                                 float* __restrict__ out) {
    __shared__ float pls[2 * 8 * PSTR];   // P double buffer
    __shared__ float zls[8 * ZSTR];       // z output buffer

    const int lane = threadIdx.x;         // 0..63, single wave
    const int bl   = lane >> 3;           // local batch 0..7
    const int j    = lane & 7;            // hidden unit owned by this lane
    const int bg   = blockIdx.x * 8;

    const float L2E = 1.4426950408889634f;
    const float NSC = -L2E;               // i,f,o scale (negated for exp2(-u))
    const float NSG = -2.0f * L2E;        // g scale (tanh u = 2*sig(2u)-1)

    // ---- recurrence weights (per lane, xor-gather order) ----
    const int ri = j, rf = 8 + j, rg_ = 16 + j, ro = 24 + j;
    float whi[8], whf[8], whg[8], who[8];
#pragma unroll
    for (int k = 0; k < 8; ++k) {
        whi[k] = W_hh[ri * 8 + (j ^ k)] * NSC;
        whf[k] = W_hh[rf * 8 + (j ^ k)] * NSC;
        whg[k] = W_hh[rg_ * 8 + (j ^ k)] * NSG;
        who[k] = W_hh[ro * 8 + (j ^ k)] * NSC;
    }
    const float wzi = W_ih[ri * 33 + 32] * NSC;
    const float wzf = W_ih[rf * 33 + 32] * NSC;
    const float wzg = W_ih[rg_ * 33 + 32] * NSG;
    const float wzo = W_ih[ro * 33 + 32] * NSC;

    // ---- head weights: full head per lane (xor-permuted cols) ----
    float w1h[5][8], b1v[5], w2v[5];
#pragma unroll
    for (int m = 0; m < 5; ++m) {
#pragma unroll
        for (int k = 0; k < 8; ++k) w1h[m][k] = W1[m * 8 + (j ^ k)];
        b1v[m] = b1[m];
        w2v[m] = W2[m];
    }
    const float b2v = b2[0];

    // ---- MFMA B fragments: N-tile0 rows 0..15 (i,f), tile1 rows 16..31 (g,o)
    const int n  = lane & 15;
    const int kq = lane >> 4;
    const int row0 = n, row1 = 16 + n;
    const float sc0 = NSC;                       // rows 0..15 all i/f
    const float sc1 = (n < 8) ? NSG : NSC;       // g rows then o rows
    bf16x8 Bh0, Bl0, Bh1, Bl1;
#pragma unroll
    for (int i = 0; i < 8; ++i) {
        const int k = kq * 8 + i;
        short h, l;
        bfsplit(W_ih[row0 * 33 + k] * sc0, h, l); Bh0[i] = h; Bl0[i] = l;
        bfsplit(W_ih[row1 * 33 + k] * sc1, h, l); Bh1[i] = h; Bl1[i] = l;
    }
    const float bias0 = (b_ih[row0] + b_hh[row0]) * sc0;
    const float bias1 = (b_ih[row1] + b_hh[row1]) * sc1;

    // A-fragment addressing: m = lane&15 -> (batch m>>1, t-parity m&1); k = kq*8..
    const int   am  = lane & 15;
    const float* xa = x + ((size_t)(bg + (am >> 1)) * T_LEN + (am & 1)) * F_IN + kq * 8;

    float4 rgv[8];
    auto load_x = [&](int ch) {   // x for chunk ch -> registers
#pragma unroll
        for (int s = 0; s < 4; ++s) {
            const float* p = xa + (size_t)(ch * TC + 2 * s) * F_IN;
            rgv[2 * s]     = *(const float4*)p;
            rgv[2 * s + 1] = *(const float4*)(p + 4);
        }
    };
    auto mfma_phase = [&](int buf) {  // P(chunk) from rgv -> pls[buf]
#pragma unroll
        for (int s = 0; s < 4; ++s) {
            const float xv[8] = {rgv[2*s].x, rgv[2*s].y, rgv[2*s].z, rgv[2*s].w,
                                 rgv[2*s+1].x, rgv[2*s+1].y, rgv[2*s+1].z, rgv[2*s+1].w};
            bf16x8 Ah, Al;
#pragma unroll
            for (int i = 0; i < 8; ++i) {
                short h, l;
                bfsplit(xv[i], h, l);
                Ah[i] = h; Al[i] = l;
            }
            floatx4 a0 = {bias0, bias0, bias0, bias0};
            floatx4 a1 = {bias1, bias1, bias1, bias1};
            a0 = __builtin_amdgcn_mfma_f32_16x16x32_bf16(Ah, Bh0, a0, 0, 0, 0);
            a0 = __builtin_amdgcn_mfma_f32_16x16x32_bf16(Al, Bh0, a0, 0, 0, 0);
            a0 = __builtin_amdgcn_mfma_f32_16x16x32_bf16(Ah, Bl0, a0, 0, 0, 0);
            a1 = __builtin_amdgcn_mfma_f32_16x16x32_bf16(Ah, Bh1, a1, 0, 0, 0);
            a1 = __builtin_amdgcn_mfma_f32_16x16x32_bf16(Al, Bh1, a1, 0, 0, 0);
            a1 = __builtin_amdgcn_mfma_f32_16x16x32_bf16(Ah, Bl1, a1, 0, 0, 0);
#pragma unroll
            for (int reg = 0; reg < 4; ++reg) {
                const int mr = (lane >> 4) * 4 + reg;      // C/D row
                const int bb = mr >> 1, tt = 2 * s + (mr & 1);
                pls[buf * 8 * PSTR + bb * PSTR + tt * 32 + n]      = a0[reg];
                pls[buf * 8 * PSTR + bb * PSTR + tt * 32 + 16 + n] = a1[reg];
            }
        }
    };

    // ---- prologue ----
    load_x(0);
    mfma_phase(0);
    load_x(1);

    float ha0 = 0.f, ha1 = 0.f, ha2 = 0.f, ha3 = 0.f,
          ha4 = 0.f, ha5 = 0.f, ha6 = 0.f, ha7 = 0.f;   // h_{j^k}
    float c = 0.0f;
    float z = z0[bg + bl];

    for (int ch = 0; ch < NCH; ++ch) {
        // prefetch this chunk's P into registers (off-chain)
        const int base = (ch & 1) * 8 * PSTR + bl * PSTR;
        float pvi[TC], pvf[TC], pvg[TC], pvo[TC];
#pragma unroll
        for (int t = 0; t < TC; ++t) {
            pvi[t] = pls[base + t * 32 + j];
            pvf[t] = pls[base + t * 32 + 8 + j];
            pvg[t] = pls[base + t * 32 + 16 + j];
            pvo[t] = pls[base + t * 32 + 24 + j];
        }

#pragma unroll
        for (int t = 0; t < TC; ++t) {
            // matvec (off z-path: starts from ha*), then +wz*z last
            float mi = fmaf(whi[0], ha0, fmaf(whi[1], ha1,
                       fmaf(whi[2], ha2, fmaf(whi[3], ha3, pvi[t]))));
            float ni = fmaf(whi[4], ha4, fmaf(whi[5], ha5,
                       fmaf(whi[6], ha6, whi[7] * ha7)));
            float mf = fmaf(whf[0], ha0, fmaf(whf[1], ha1,
                       fmaf(whf[2], ha2, fmaf(whf[3], ha3, pvf[t]))));
            float nf = fmaf(whf[4], ha4, fmaf(whf[5], ha5,
                       fmaf(whf[6], ha6, whf[7] * ha7)));
            float mg = fmaf(whg[0], ha0, fmaf(whg[1], ha1,
                       fmaf(whg[2], ha2, fmaf(whg[3], ha3, pvg[t]))));
            float ng = fmaf(whg[4], ha4, fmaf(whg[5], ha5,
                       fmaf(whg[6], ha6, whg[7] * ha7)));
            float mo = fmaf(who[0], ha0, fmaf(who[1], ha1,
                       fmaf(who[2], ha2, fmaf(who[3], ha3, pvo[t]))));
            float no = fmaf(who[4], ha4, fmaf(who[5], ha5,
                       fmaf(who[6], ha6, who[7] * ha7)));

            const float ai = fmaf(wzi, z, mi + ni);
            const float af = fmaf(wzf, z, mf + nf);
            const float ag = fmaf(wzg, z, mg + ng);
            const float ao = fmaf(wzo, z, mo + no);

            // activations: acc pre-scaled by -log2e (or -2log2e for g)
            const float si = __builtin_amdgcn_rcpf(1.0f + __builtin_amdgcn_exp2f(ai));
            const float sf = __builtin_amdgcn_rcpf(1.0f + __builtin_amdgcn_exp2f(af));
            const float sg = __builtin_amdgcn_rcpf(1.0f + __builtin_amdgcn_exp2f(ag));
            const float so = __builtin_amdgcn_rcpf(1.0f + __builtin_amdgcn_exp2f(ao));
            const float tg = fmaf(2.0f, sg, -1.0f);      // tanh(g)

            c = fmaf(sf, c, si * tg);
            const float ec = __builtin_amdgcn_exp2f(c * (-2.0f * L2E));
            const float tc = fmaf(2.0f, __builtin_amdgcn_rcpf(1.0f + ec), -1.0f);
            const float hn = so * tc;                    // h_j

            // gather h_{j^k}: pure DPP within the 8-lane group, depth 2
            ha0 = hn;
            ha1 = dppf<QP(1, 0, 3, 2)>(hn);
            ha2 = dppf<QP(2, 3, 0, 1)>(hn);
            ha3 = dppf<QP(3, 2, 1, 0)>(hn);
            const float t7 = dppf<DPP_HM>(hn);
            ha7 = t7;
            ha4 = dppf<QP(3, 2, 1, 0)>(t7);
            ha5 = dppf<QP(2, 3, 0, 1)>(t7);
            ha6 = dppf<QP(1, 0, 3, 2)>(t7);

            // head: fully per-lane (redundant x8, zero cross-lane)
            float d0a = fmaf(w1h[0][0], ha0, fmaf(w1h[0][1], ha1, fmaf(w1h[0][2], ha2, b1v[0])));
            float d0b = fmaf(w1h[0][4], ha4, fmaf(w1h[0][5], ha5, fmaf(w1h[0][6], ha6, w1h[0][7] * ha7)));
            float d1a = fmaf(w1h[1][0], ha0, fmaf(w1h[1][1], ha1, fmaf(w1h[1][2], ha2, b1v[1])));
            float d1b = fmaf(w1h[1][4], ha4, fmaf(w1h[1][5], ha5, fmaf(w1h[1][6], ha6, w1h[1][7] * ha7)));
            float d2a = fmaf(w1h[2][0], ha0, fmaf(w1h[2][1], ha1, fmaf(w1h[2][2], ha2, b1v[2])));
            float d2b = fmaf(w1h[2][4], ha4, fmaf(w1h[2][5], ha5, fmaf(w1h[2][6], ha6, w1h[2][7] * ha7)));
            float d3a = fmaf(w1h[3][0], ha0, fmaf(w1h[3][1], ha1, fmaf(w1h[3][2], ha2, b1v[3])));
            float d3b = fmaf(w1h[3][4], ha4, fmaf(w1h[3][5], ha5, fmaf(w1h[3][6], ha6, w1h[3][7] * ha7)));
            float d4a = fmaf(w1h[4][0], ha0, fmaf(w1h[4][1], ha1, fmaf(w1h[4][2], ha2, b1v[4])));
            float d4b = fmaf(w1h[4][4], ha4, fmaf(w1h[4][5], ha5, fmaf(w1h[4][6], ha6, w1h[4][7] * ha7)));
            const float d0 = fmaxf(fmaf(w1h[0][3], ha3, d0a + d0b), 0.0f);
            const float d1 = fmaxf(fmaf(w1h[1][3], ha3, d1a + d1b), 0.0f);
            const float d2 = fmaxf(fmaf(w1h[2][3], ha3, d2a + d2b), 0.0f);
            const float d3 = fmaxf(fmaf(w1h[3][3], ha3, d3a + d3b), 0.0f);
            const float d4 = fmaxf(fmaf(w1h[4][3], ha3, d4a + d4b), 0.0f);
            const float q1 = fmaf(w2v[0], d0, fmaf(w2v[1], d1, b2v));
            const float q2 = fmaf(w2v[2], d2, fmaf(w2v[3], d3, w2v[4] * d4));
            z += fmaxf(q1 + q2, 0.0f);

            if (j == t) zls[bl * ZSTR + ch * TC + t] = z;
        }

        if (ch + 1 < NCH) {
            mfma_phase((ch + 1) & 1);           // P(ch+1) from rgv
            if (ch + 2 < NCH) load_x(ch + 2);   // start next global loads
        }
    }

    // coalesced output store (single wave; LDS ordering via waitcnt)
    __builtin_amdgcn_s_waitcnt(0);  // lgkmcnt(0)&vmcnt(0): zls writes visible
#pragma unroll
    for (int it = 0; it < 7; ++it) {
        const int idx = lane + it * 64;          // float4 index, 400 total
        if (idx < 8 * (T_LEN / 4)) {
            const int bb = idx / 50, rem = idx - bb * 50;
            *(float4*)&out[(size_t)(bg + bb) * T_LEN + rem * 4] =
                *(const float4*)&zls[bb * ZSTR + rem * 4];
        }
    }
}

extern "C" void kernel_launch(void* const* d_in, const int* in_sizes, int n_in,
                              void* d_out, int out_size, void* d_ws, size_t ws_size,
                              hipStream_t stream) {
    const float* x    = (const float*)d_in[0];
    const float* z0   = (const float*)d_in[1];
    const float* W_ih = (const float*)d_in[2];
    const float* W_hh = (const float*)d_in[3];
    const float* b_ih = (const float*)d_in[4];
    const float* b_hh = (const float*)d_in[5];
    const float* W1   = (const float*)d_in[6];
    const float* b1   = (const float*)d_in[7];
    const float* W2   = (const float*)d_in[8];
    const float* b2   = (const float*)d_in[9];
    float* out = (float*)d_out;

    const int B = in_sizes[1];
    dim3 grid(B / 8), block(64);
    hipLaunchKernelGGL(mono_lstm_kernel, grid, block, 0, stream,
                       x, z0, W_ih, W_hh, b_ih, b_hh, W1, b1, W2, b2, out);
}